// Round 2
// baseline (5997.528 us; speedup 1.0000x reference)
//
#include <hip/hip_runtime.h>
#include <cstdint>
#include <cstddef>

#define DEVI __device__ __forceinline__

namespace {

constexpr int T_B = 128;
constexpr int T_N = 48;
constexpr int NP1 = 49;          // n+1 (ghost node)
constexpr int NOUT = T_B * T_N * 4 * NP1;   // 1,204,224 per output tensor

DEVI unsigned rotl(unsigned x, int d) { return (x << d) | (x >> (32 - d)); }

// JAX threefry, PARTITIONABLE mode (default since jax 0.4.30):
// per-element counter i (uint64 iota) -> block inputs (hi32(i), lo32(i));
// for size < 2^32 that is (0, i). 32-bit output = out0 ^ out1.
// Then uniform: bitcast((bits>>9)|0x3f800000)-1, max(0); exponential:
// -log1p(-u); gumbel: -log(exponential).
DEVI float gumbel_noise(unsigned idx) {
  unsigned x0 = 0u, x1 = idx;
  const unsigned k0 = 0u, k1 = 42u, k2 = 0x1BD11BDAu ^ 0u ^ 42u;
  x0 += k0; x1 += k1;
#define TF_R(rr) { x0 += x1; x1 = rotl(x1, rr); x1 ^= x0; }
  TF_R(13) TF_R(15) TF_R(26) TF_R(6)   x0 += k1; x1 += k2 + 1u;
  TF_R(17) TF_R(29) TF_R(16) TF_R(24)  x0 += k2; x1 += k0 + 2u;
  TF_R(13) TF_R(15) TF_R(26) TF_R(6)   x0 += k0; x1 += k1 + 3u;
  TF_R(17) TF_R(29) TF_R(16) TF_R(24)  x0 += k1; x1 += k2 + 4u;
  TF_R(13) TF_R(15) TF_R(26) TF_R(6)   x0 += k2; x1 += k0 + 5u;
#undef TF_R
  const unsigned bits = x0 ^ x1;
  float u = __uint_as_float((bits >> 9) | 0x3f800000u) - 1.0f;  // [0,1)
  u = fmaxf(u, 0.0f);
  const float ex = -log1pf(-u);   // exponential sample
  return -logf(ex);               // gumbel
}

#define ACC4(ACC, FA, MA, MB, MC, MD)                                   \
  ACC[0] += FA.x * MA.x + FA.y * MB.x + FA.z * MC.x + FA.w * MD.x;      \
  ACC[1] += FA.x * MA.y + FA.y * MB.y + FA.z * MC.y + FA.w * MD.y;      \
  ACC[2] += FA.x * MA.z + FA.y * MB.z + FA.z * MC.z + FA.w * MD.z;      \
  ACC[3] += FA.x * MA.w + FA.y * MB.w + FA.z * MC.w + FA.w * MD.w;

}  // namespace

// One block per (batch, target). Phases:
//  0: stage attn_mask, compute mask_ped, build feat[49][96] in LDS
//  1: E = LayerNorm(feat @ W_embed + b) -> LDS [49][128]
//  2: qkv = E @ W_qkv + b (accumulated in registers, then stored over dead
//     LDS regions: qT[4][32][49] over E, k/v[4][49][32] over feat/mask)
//  3: per-head wave: scores/softmax/PV/gating in registers, masked em
//     softmax, threefry gumbel, sampled softmax. Writes both outputs.
// LDS arena = 18816 floats (75,264 B) + W1t etc = 79,816 B -> 2 blocks/CU.
__global__ __launch_bounds__(256, 2) void edge_selector_kernel(
    const float* __restrict__ x, const float* __restrict__ A,
    const float* __restrict__ amask, const float* __restrict__ Wemb,
    const float* __restrict__ bemb, const float* __restrict__ gamma_,
    const float* __restrict__ beta_, const float* __restrict__ Wqkv,
    const float* __restrict__ bqkv, const float* __restrict__ W1g,
    const float* __restrict__ b1g, const float* __restrict__ W2g,
    const float* __restrict__ b2g, float* __restrict__ out) {
  __shared__ __align__(16) float F[18816];
  __shared__ __align__(16) float sW1t[32 * 32];  // W1 transposed: [f][e]
  __shared__ float sM[NP1];
  __shared__ float sB1[32];
  __shared__ float sW2s[32];
  __shared__ float sB2;

  float* const sE    = F;             // [49][128]  (phases 1-2)
  float* const sFeat = F + 6272;      // [49][96]   (phases 0-1)
  float* const sAM   = F + 10976;     // [48][48]   (phase 0)
  float* const sMp   = F + 13280;     // [48]       (phase 0)
  float* const sQT   = F;             // [4][32][49] (phase 3, over sE)
  float* const sK    = F + 6272;      // [4][49][32] (phase 3)
  float* const sV    = F + 12544;     // [4][49][32] (phase 3)

  const int t  = threadIdx.x;
  const int tg = blockIdx.x;
  const int bb = blockIdx.y;

  // ---------------- phase 0a: stage masks & small weights ----------------
  for (int idx = t; idx < 48 * 48; idx += 256) sAM[idx] = amask[bb * 2304 + idx];
  for (int idx = t; idx < 1024; idx += 256) {
    const int e = idx >> 5, f = idx & 31;
    sW1t[f * 32 + e] = W1g[idx];
  }
  if (t < 32) { sB1[t] = b1g[t]; sW2s[t] = W2g[t]; }
  if (t == 0) sB2 = b2g[0];
  __syncthreads();
  if (t < 48) {
    float s = 0.f;
    for (int j = 0; j < 48; ++j) s += sAM[t * 48 + j];
    sMp[t] = (s > 0.f) ? 1.f : 0.f;
    sM[t] = sAM[tg * 48 + t];
  }
  if (t == 0) sM[48] = 1.f;   // ghost column always attendable
  __syncthreads();

  // ---------------- phase 0b: feat = [xn[nb], x[tg], A'[nb,tg]] ----------
  {
    const float mt = sMp[tg];
    for (int idx = t; idx < NP1 * 32; idx += 256) {
      const int nb = idx >> 5, e = idx & 31;
      sFeat[nb * 96 + 32 + e] = x[(bb * 48 + tg) * 32 + e] * mt;
      float xv = 0.f, av = 0.f;
      if (nb < 48) {
        xv = x[(bb * 48 + nb) * 32 + e] * sMp[nb];
        av = A[(((bb * 48 + nb) * 48) + tg) * 32 + e] * sAM[tg * 48 + nb];
      }
      sFeat[nb * 96 + e]      = xv;
      sFeat[nb * 96 + 64 + e] = av;
    }
  }
  __syncthreads();

  const int dq   = t & 31;                 // output column quad (d = dq*4)
  const int nbq  = t >> 5;                 // row group
  const int nrow = (nbq == 0) ? 7 : 6;
  int nbr[7];
#pragma unroll
  for (int r = 0; r < 7; ++r) nbr[r] = (r == 6) ? 48 : (nbq + 8 * r);

  // ---------------- phase 1: E = LN(feat @ Wemb + bemb) ------------------
  {
    float acc[7][4];
#pragma unroll
    for (int r = 0; r < 7; ++r)
#pragma unroll
      for (int c = 0; c < 4; ++c) acc[r][c] = 0.f;

    for (int kc = 0; kc < 96; kc += 8) {
      float4 w[8];
#pragma unroll
      for (int kk = 0; kk < 8; ++kk)
        w[kk] = *(const float4*)&Wemb[(kc + kk) * 128 + dq * 4];
#pragma unroll
      for (int r = 0; r < 7; ++r)
        if (r < nrow) {
          const float* fr = &sFeat[nbr[r] * 96 + kc];
          const float4 fa = *(const float4*)fr;
          const float4 fb = *(const float4*)(fr + 4);
          ACC4(acc[r], fa, w[0], w[1], w[2], w[3]);
          ACC4(acc[r], fb, w[4], w[5], w[6], w[7]);
        }
    }
    const float4 be = *(const float4*)&bemb[dq * 4];
    const float4 gm = *(const float4*)&gamma_[dq * 4];
    const float4 bt = *(const float4*)&beta_[dq * 4];
#pragma unroll
    for (int r = 0; r < 7; ++r)
      if (r < nrow) {
        const float e0 = acc[r][0] + be.x, e1 = acc[r][1] + be.y;
        const float e2 = acc[r][2] + be.z, e3 = acc[r][3] + be.w;
        float s  = e0 + e1 + e2 + e3;
        float qs = e0 * e0 + e1 * e1 + e2 * e2 + e3 * e3;
#pragma unroll
        for (int md = 16; md; md >>= 1) {
          s  += __shfl_xor(s, md, 32);
          qs += __shfl_xor(qs, md, 32);
        }
        const float mu  = s * (1.0f / 128.0f);
        const float var = qs * (1.0f / 128.0f) - mu * mu;
        const float rs  = 1.0f / sqrtf(var + 1e-5f);
        float4 o;
        o.x = (e0 - mu) * rs * gm.x + bt.x;
        o.y = (e1 - mu) * rs * gm.y + bt.y;
        o.z = (e2 - mu) * rs * gm.z + bt.z;
        o.w = (e3 - mu) * rs * gm.w + bt.w;
        *(float4*)&sE[nbr[r] * 128 + dq * 4] = o;
      }
  }
  __syncthreads();

  // ---------------- phase 2: qkv = E @ Wqkv + b (regs) -------------------
  {
    float qa[7][4], ka[7][4], va[7][4];
#pragma unroll
    for (int r = 0; r < 7; ++r)
#pragma unroll
      for (int c = 0; c < 4; ++c) { qa[r][c] = 0.f; ka[r][c] = 0.f; va[r][c] = 0.f; }

    for (int kc = 0; kc < 128; kc += 4) {
      float4 ef[7];
#pragma unroll
      for (int r = 0; r < 7; ++r)
        if (r < nrow) ef[r] = *(const float4*)&sE[nbr[r] * 128 + kc];
#pragma unroll
      for (int p = 0; p < 3; ++p) {
        const float* wp = &Wqkv[kc * 384 + p * 128 + dq * 4];
        const float4 w0 = *(const float4*)wp;
        const float4 w1 = *(const float4*)(wp + 384);
        const float4 w2 = *(const float4*)(wp + 768);
        const float4 w3 = *(const float4*)(wp + 1152);
        float(*ap)[4] = (p == 0) ? qa : (p == 1) ? ka : va;
#pragma unroll
        for (int r = 0; r < 7; ++r)
          if (r < nrow) {
            const float4 f = ef[r];
            ACC4(ap[r], f, w0, w1, w2, w3);
          }
      }
    }
    __syncthreads();  // all E reads done; safe to overwrite with qT/k/v
    const int h  = dq >> 3;
    const int e0 = (dq & 7) * 4;
    const float4 bqv = *(const float4*)&bqkv[dq * 4];
    const float4 bkv = *(const float4*)&bqkv[128 + dq * 4];
    const float4 bvv = *(const float4*)&bqkv[256 + dq * 4];
    const float SC = 0.17677669529663687f;  // 1/sqrt(32)
#pragma unroll
    for (int r = 0; r < 7; ++r)
      if (r < nrow) {
        const int nb = nbr[r];
        sQT[(h * 32 + e0 + 0) * 49 + nb] = (qa[r][0] + bqv.x) * SC;
        sQT[(h * 32 + e0 + 1) * 49 + nb] = (qa[r][1] + bqv.y) * SC;
        sQT[(h * 32 + e0 + 2) * 49 + nb] = (qa[r][2] + bqv.z) * SC;
        sQT[(h * 32 + e0 + 3) * 49 + nb] = (qa[r][3] + bqv.w) * SC;
        float4 ko, vo;
        ko.x = ka[r][0] + bkv.x; ko.y = ka[r][1] + bkv.y;
        ko.z = ka[r][2] + bkv.z; ko.w = ka[r][3] + bkv.w;
        vo.x = va[r][0] + bvv.x; vo.y = va[r][1] + bvv.y;
        vo.z = va[r][2] + bvv.z; vo.w = va[r][3] + bvv.w;
        *(float4*)&sK[(h * 49 + nb) * 32 + e0] = ko;
        *(float4*)&sV[(h * 49 + nb) * 32 + e0] = vo;
      }
  }
  __syncthreads();

  // ---------------- phase 3: attention + gating + em + sampled -----------
  {
    const int wh   = t >> 6;       // head (one wave per head)
    const int lane = t & 63;
    const bool act = lane < NP1;
    const int i    = act ? lane : 0;

    float qreg[32];
#pragma unroll
    for (int e = 0; e < 32; ++e) qreg[e] = sQT[(wh * 32 + e) * 49 + i];
    const float mi = act ? sM[i] : 0.f;
    const bool mj = act ? (sM[lane] > 0.f) : false;
    const unsigned long long mbits = __ballot(mj);

    float S[NP1];
#pragma unroll
    for (int j = 0; j < NP1; ++j) {
      const float4* kr = (const float4*)&sK[(wh * 49 + j) * 32];
      float a = 0.f;
#pragma unroll
      for (int eq = 0; eq < 8; ++eq) {
        const float4 k4 = kr[eq];
        a += qreg[eq * 4 + 0] * k4.x + qreg[eq * 4 + 1] * k4.y +
             qreg[eq * 4 + 2] * k4.z + qreg[eq * 4 + 3] * k4.w;
      }
      S[j] = a;
    }
    const bool rowok = mi > 0.f;
#pragma unroll
    for (int j = 0; j < NP1; ++j) {
      const bool ok = rowok && ((mbits >> j) & 1ull);
      S[j] = ok ? S[j] : -1e9f;
    }
    float mx = S[0];
#pragma unroll
    for (int j = 1; j < NP1; ++j) mx = fmaxf(mx, S[j]);
    float ssum = 0.f;
#pragma unroll
    for (int j = 0; j < NP1; ++j) { S[j] = expf(S[j] - mx); ssum += S[j]; }
    const float sinv = 1.0f / ssum;
#pragma unroll
    for (int j = 0; j < NP1; ++j) S[j] *= sinv;

    float A2r[32];
#pragma unroll
    for (int e = 0; e < 32; ++e) A2r[e] = 0.f;
#pragma unroll
    for (int j = 0; j < NP1; ++j) {
      const float4* vr = (const float4*)&sV[(wh * 49 + j) * 32];
#pragma unroll
      for (int eq = 0; eq < 8; ++eq) {
        const float4 v4 = vr[eq];
        A2r[eq * 4 + 0] += S[j] * v4.x;
        A2r[eq * 4 + 1] += S[j] * v4.y;
        A2r[eq * 4 + 2] += S[j] * v4.z;
        A2r[eq * 4 + 3] += S[j] * v4.w;
      }
    }

    // gating MLP: s2 = W2 . relu(W1^T A2 + b1) + b2
    float s2 = sB2;
#pragma unroll
    for (int f = 0; f < 32; ++f) {
      const float4* wr = (const float4*)&sW1t[f * 32];
      float a = sB1[f];
#pragma unroll
      for (int eq = 0; eq < 8; ++eq) {
        const float4 w4 = wr[eq];
        a += A2r[eq * 4 + 0] * w4.x + A2r[eq * 4 + 1] * w4.y +
             A2r[eq * 4 + 2] * w4.z + A2r[eq * 4 + 3] * w4.w;
      }
      s2 += fmaxf(a, 0.f) * sW2s[f];
    }

    // em = normalize(softmax_i(s2) * m)
    const float v0 = act ? s2 : -1e30f;
    float mx2 = v0;
#pragma unroll
    for (int md = 32; md; md >>= 1) mx2 = fmaxf(mx2, __shfl_xor(mx2, md));
    float p = act ? expf(v0 - mx2) : 0.f;
    float ps = p;
#pragma unroll
    for (int md = 32; md; md >>= 1) ps += __shfl_xor(ps, md);
    float em = (p / ps) * mi;
    float es = em;
#pragma unroll
    for (int md = 32; md; md >>= 1) es += __shfl_xor(es, md);
    em = em / (es + 1e-10f);

    const int base = ((bb * 48 + tg) * 4 + wh) * 49;
    if (act) out[base + lane] = em;

    // sampled = softmax(log(em + 1e-10) + gumbel)
    const float lg = logf(em + 1e-10f);
    const float gn = gumbel_noise((unsigned)(base + lane));
    const float z = act ? (lg + gn) : -1e30f;
    float mx3 = z;
#pragma unroll
    for (int md = 32; md; md >>= 1) mx3 = fmaxf(mx3, __shfl_xor(mx3, md));
    float p3 = act ? expf(z - mx3) : 0.f;
    float ps3 = p3;
#pragma unroll
    for (int md = 32; md; md >>= 1) ps3 += __shfl_xor(ps3, md);
    if (act) out[NOUT + base + lane] = p3 / ps3;
  }
}

extern "C" void kernel_launch(void* const* d_in, const int* in_sizes, int n_in,
                              void* d_out, int out_size, void* d_ws, size_t ws_size,
                              hipStream_t stream) {
  (void)in_sizes; (void)n_in; (void)out_size; (void)d_ws; (void)ws_size;
  const float* x    = (const float*)d_in[0];
  const float* A    = (const float*)d_in[1];
  const float* am   = (const float*)d_in[2];
  const float* Wemb = (const float*)d_in[3];
  const float* bemb = (const float*)d_in[4];
  const float* gm   = (const float*)d_in[5];
  const float* bt   = (const float*)d_in[6];
  const float* Wqkv = (const float*)d_in[7];
  const float* bqkv = (const float*)d_in[8];
  const float* W1   = (const float*)d_in[9];
  const float* b1   = (const float*)d_in[10];
  const float* W2   = (const float*)d_in[11];
  const float* b2   = (const float*)d_in[12];
  dim3 grid(T_N, T_B);
  edge_selector_kernel<<<grid, 256, 0, stream>>>(
      x, A, am, Wemb, bemb, gm, bt, Wqkv, bqkv, W1, b1, W2, b2, (float*)d_out);
}